// Round 8
// baseline (10334.538 us; speedup 1.0000x reference)
//
#include <hip/hip_runtime.h>
#include <math.h>

#define DIM   768
#define NHEAD 16
#define DHEAD 48
#define NLAY  3
#define NTOK  256
#define BATCH 4
#define NPAST_ 16
#define NFUT  20
#define CCTX  273              // NTOK + 1 + NPAST
#define SMAXT 293              // CCTX + NFUT
#define MROWS 1172             // BATCH * SMAXT
#define NEGV  (-1.0e9f)
#define QKVPLANE 900096        // BATCH*NHEAD*SMAXT*48
#define STSTRIDE 52            // per-row softmax state: 48 oacc + m + l (+pad)

typedef unsigned short u16;
typedef unsigned int   u32;
typedef __attribute__((ext_vector_type(8))) short short8;
typedef __attribute__((ext_vector_type(4))) float floatx4;

__device__ inline u16 f2bf(float x) {
    union { float f; u32 u; } v; v.f = x;
    u32 r = v.u + 0x7fffu + ((v.u >> 16) & 1u);
    return (u16)(r >> 16);
}

__device__ inline float bf2f(u16 x) {
    union { u32 u; float f; } c; c.u = ((u32)x) << 16;
    return c.f;
}

__device__ inline float gelu_f(float x) {
    return 0.5f * x * (1.0f + erff(x * 0.70710678118654752f));
}

// ---------------------------------------------------------------- init X_base
__global__ void init_base(const float* __restrict__ img, const float* __restrict__ past,
                          const int* __restrict__ intent, const float* __restrict__ pos,
                          const float* __restrict__ futq, const float* __restrict__ iemb,
                          const float* __restrict__ temb, const float* __restrict__ Wp,
                          const float* __restrict__ bp, const float* __restrict__ Wpp,
                          const float* __restrict__ bpp, float* __restrict__ X)
{
    int r = blockIdx.x;
    int b = r / SMAXT, s = r % SMAXT;
    for (int j = threadIdx.x; j < DIM; j += blockDim.x) {
        float v;
        if (s < NTOK) {
            v = img[(long)(b * NTOK + s) * DIM + j] + pos[(long)s * DIM + j];
        } else if (s == NTOK) {
            int idx = intent[b] - 1; idx = idx < 0 ? 0 : (idx > 2 ? 2 : idx);
            v = iemb[(long)idx * DIM + j];
        } else if (s < CCTX) {
            int i = s - (NTOK + 1);
            v = bp[j] + bpp[j] + temb[(long)i * DIM + j];
            const float* pr = past + (long)(b * NPAST_ + i) * 6;
            #pragma unroll
            for (int c = 0; c < 6; ++c) v += pr[c] * Wp[(long)c * DIM + j];
            v += pr[0] * Wpp[j] + pr[1] * Wpp[DIM + j];
        } else {
            int f = s - CCTX;
            v = futq[(long)f * DIM + j] + temb[(long)(NPAST_ + f) * DIM + j];
        }
        X[(long)r * DIM + j] = v;
    }
}

// ---------------------------------------------------------------- weight convert + transpose: W[K,N] fp32 -> Wt[N,K] bf16
__global__ void convert_transpose(const float* __restrict__ W, u16* __restrict__ Wt, int K, int N)
{
    __shared__ float tile[32][33];
    long lstride = (long)K * N;
    W  += blockIdx.z * lstride;
    Wt += blockIdx.z * lstride;
    int n0 = blockIdx.x * 32, k0 = blockIdx.y * 32;
    int tx = threadIdx.x & 31, ty = threadIdx.x >> 5;
    for (int i = ty; i < 32; i += 8)
        tile[i][tx] = W[(long)(k0 + i) * N + n0 + tx];
    __syncthreads();
    for (int i = ty; i < 32; i += 8)
        Wt[(long)(n0 + i) * K + k0 + tx] = f2bf(tile[tx][i]);
}

// ---------------------------------------------------------------- layernorm -> bf16 (all rows)
__launch_bounds__(256)
__global__ void ln_kernel(const float* __restrict__ x, const float* __restrict__ g,
                          const float* __restrict__ be, u16* __restrict__ y)
{
    int row = blockIdx.x * 4 + (threadIdx.x >> 6);
    int lane = threadIdx.x & 63;
    if (row >= MROWS) return;
    const float* xr = x + (long)row * DIM;
    float v[12];
    float s = 0.f;
    #pragma unroll
    for (int i = 0; i < 12; ++i) { v[i] = xr[lane + 64 * i]; s += v[i]; }
    for (int off = 32; off; off >>= 1) s += __shfl_down(s, off, 64);
    s = __shfl(s, 0, 64);
    float mean = s * (1.f / 768.f);
    float vs = 0.f;
    #pragma unroll
    for (int i = 0; i < 12; ++i) { float d = v[i] - mean; vs += d * d; }
    for (int off = 32; off; off >>= 1) vs += __shfl_down(vs, off, 64);
    vs = __shfl(vs, 0, 64);
    float inv = rsqrtf(vs * (1.f / 768.f) + 1e-5f);
    u16* yr = y + (long)row * DIM;
    #pragma unroll
    for (int i = 0; i < 12; ++i) {
        int j = lane + 64 * i;
        yr[j] = f2bf((v[i] - mean) * inv * g[j] + be[j]);
    }
}

// ---------------------------------------------------------------- layernorm of the 4 rows (b*SMAXT + S-1) only
__launch_bounds__(256)
__global__ void ln4_kernel(const float* __restrict__ x, const float* __restrict__ g,
                           const float* __restrict__ be, u16* __restrict__ y, int S)
{
    int b = threadIdx.x >> 6;
    int lane = threadIdx.x & 63;
    long row = (long)b * SMAXT + (S - 1);
    const float* xr = x + row * DIM;
    float v[12];
    float s = 0.f;
    #pragma unroll
    for (int i = 0; i < 12; ++i) { v[i] = xr[lane + 64 * i]; s += v[i]; }
    for (int off = 32; off; off >>= 1) s += __shfl_down(s, off, 64);
    s = __shfl(s, 0, 64);
    float mean = s * (1.f / 768.f);
    float vs = 0.f;
    #pragma unroll
    for (int i = 0; i < 12; ++i) { float d = v[i] - mean; vs += d * d; }
    for (int off = 32; off; off >>= 1) vs += __shfl_down(vs, off, 64);
    vs = __shfl(vs, 0, 64);
    float inv = rsqrtf(vs * (1.f / 768.f) + 1e-5f);
    u16* yr = y + row * DIM;
    #pragma unroll
    for (int i = 0; i < 12; ++i) {
        int j = lane + 64 * i;
        yr[j] = f2bf((v[i] - mean) * inv * g[j] + be[j]);
    }
}

// ---------------------------------------------------------------- bf16 MFMA GEMM (verified structure; + LN-fusion, + split-K)
// Plain (LNF=false): A[M,K] bf16 row-major.  LNF=true: A is ignored; xs[M,768] fp32
// is layer-normed on the fly (per-row stats computed in-block with the EXACT
// ln_kernel reduction pattern -> staged bf16 bits identical to the 2-kernel path).
// Wt[N,K] bf16 row-major.  C = A @ Wt^T + bias.
// MODE 0: out fp32, += res.  MODE 1: relu, out bf16.  MODE 2: qkv-permuted fp32.
// MODE 3 (KSPLIT>1): atomicAdd into out (residual pre-resident); bias added by kz==0.
template<int BM, int BN, int MODE, bool LNF, int KSPLIT>
__launch_bounds__(256)
__global__ void gemm_mfma(const u16* __restrict__ A, const float* __restrict__ xs,
                          const float* __restrict__ lng, const float* __restrict__ lnb,
                          const u16* __restrict__ Wt,
                          const float* __restrict__ bias, const float* __restrict__ res,
                          void* __restrict__ outv, int M, int N, int K, int n0base)
{
    constexpr int MFRAG = BM / 16;
    constexpr int MI = MFRAG / 2;
    constexpr int NSUB = BN / 16;
    constexpr int NJ = NSUB / 2;
    constexpr int NA = (BM * 8) / 256;
    constexpr int NB = (BN * 8) / 256;
    __shared__ u16 As[2 * MFRAG * 64 * 8];
    __shared__ u16 Bs[2 * NSUB * 64 * 8];
    __shared__ float smu[BM], siv[BM];

    int tid = threadIdx.x;
    int lane = tid & 63;
    int w = tid >> 6, wm = w >> 1, wn = w & 1;
    int m0 = blockIdx.y * BM, n0 = n0base + blockIdx.x * BN;

    if constexpr (LNF) {
        // per-row LN stats, bit-identical to ln_kernel's reduction
        #pragma unroll 1
        for (int rr = 0; rr < BM / 4; ++rr) {
            int r = w * (BM / 4) + rr;
            int gr = m0 + r; if (gr >= M) gr = M - 1;
            const float* xr = xs + (long)gr * 768;
            float v[12];
            float s = 0.f;
            #pragma unroll
            for (int i = 0; i < 12; ++i) { v[i] = xr[lane + 64 * i]; s += v[i]; }
            for (int off = 32; off; off >>= 1) s += __shfl_down(s, off, 64);
            s = __shfl(s, 0, 64);
            float mean = s * (1.f / 768.f);
            float vs = 0.f;
            #pragma unroll
            for (int i = 0; i < 12; ++i) { float d = v[i] - mean; vs += d * d; }
            for (int off = 32; off; off >>= 1) vs += __shfl_down(vs, off, 64);
            vs = __shfl(vs, 0, 64);
            float inv = rsqrtf(vs * (1.f / 768.f) + 1e-5f);
            if (lane == 0) { smu[r] = mean; siv[r] = inv; }
        }
    }

    floatx4 acc[MI][NJ];
    #pragma unroll
    for (int i = 0; i < MI; ++i)
        #pragma unroll
        for (int j = 0; j < NJ; ++j) acc[i][j] = (floatx4){0.f, 0.f, 0.f, 0.f};

    int lm = lane & 15, lk = lane >> 4;      // fragment (m, kgroup)

    int ksz = K / KSPLIT;
    int kb = (KSPLIT > 1) ? blockIdx.z * ksz : 0;
    for (int k0 = kb; k0 < kb + ksz; k0 += 64) {
        __syncthreads();
        #pragma unroll
        for (int i = 0; i < NA; ++i) {       // A: BM rows x 8 chunks
            int q = tid + 256 * i;
            int r = q >> 3, c = q & 7;
            int gr = m0 + r; if (gr >= M) gr = M - 1;
            int off = (((c >> 2) * MFRAG + (r >> 4)) * 64 + (r & 15) * 4 + (c & 3)) * 8;
            if constexpr (LNF) {
                const float* xp = xs + (long)gr * 768 + k0 + c * 8;
                float4 f0 = *(const float4*)(xp);
                float4 f1 = *(const float4*)(xp + 4);
                float4 ga = *(const float4*)(lng + k0 + c * 8);
                float4 gb = *(const float4*)(lng + k0 + c * 8 + 4);
                float4 ba = *(const float4*)(lnb + k0 + c * 8);
                float4 bb = *(const float4*)(lnb + k0 + c * 8 + 4);
                float mu = smu[r], iv = siv[r];
                short8 pk;
                pk[0] = (short)f2bf((f0.x - mu) * iv * ga.x + ba.x);
                pk[1] = (short)f2bf((f0.y - mu) * iv * ga.y + ba.y);
                pk[2] = (short)f2bf((f0.z - mu) * iv * ga.z + ba.z);
                pk[3] = (short)f2bf((f0.w - mu) * iv * ga.w + ba.w);
                pk[4] = (short)f2bf((f1.x - mu) * iv * gb.x + bb.x);
                pk[5] = (short)f2bf((f1.y - mu) * iv * gb.y + bb.y);
                pk[6] = (short)f2bf((f1.z - mu) * iv * gb.z + bb.z);
                pk[7] = (short)f2bf((f1.w - mu) * iv * gb.w + bb.w);
                *(int4*)&As[off] = *(int4*)&pk;
            } else {
                int4 v = *(const int4*)(A + (long)gr * K + k0 + c * 8);
                *(int4*)&As[off] = v;
            }
        }
        #pragma unroll
        for (int i = 0; i < NB; ++i) {       // B: BN rows x 8 chunks
            int q = tid + 256 * i;
            int r = q >> 3, c = q & 7;
            int4 v = *(const int4*)(Wt + (long)(n0 + r) * K + k0 + c * 8);
            int off = (((c >> 2) * NSUB + (r >> 4)) * 64 + (r & 15) * 4 + (c & 3)) * 8;
            *(int4*)&Bs[off] = v;
        }
        __syncthreads();
        #pragma unroll
        for (int t = 0; t < 2; ++t) {
            short8 af[MI];
            #pragma unroll
            for (int i = 0; i < MI; ++i)
                af[i] = *(const short8*)&As[((t * MFRAG + wm * MI + i) * 64 + lm * 4 + lk) * 8];
            short8 bfr[NJ];
            #pragma unroll
            for (int j = 0; j < NJ; ++j)
                bfr[j] = *(const short8*)&Bs[((t * NSUB + wn * NJ + j) * 64 + lm * 4 + lk) * 8];
            #pragma unroll
            for (int i = 0; i < MI; ++i)
                #pragma unroll
                for (int j = 0; j < NJ; ++j)
                    acc[i][j] = __builtin_amdgcn_mfma_f32_16x16x32_bf16(af[i], bfr[j], acc[i][j], 0, 0, 0);
        }
    }

    #pragma unroll
    for (int j = 0; j < NJ; ++j) {
        int col = n0 + wn * (NJ * 16) + j * 16 + lm;
        float bv = bias[col];
        #pragma unroll
        for (int i = 0; i < MI; ++i) {
            int rbase = m0 + wm * (MI * 16) + i * 16 + lk * 4;
            #pragma unroll
            for (int rr = 0; rr < 4; ++rr) {
                int row = rbase + rr;
                if (row >= M) continue;
                if (MODE == 3) {
                    float val = acc[i][j][rr] + (blockIdx.z == 0 ? bv : 0.f);
                    atomicAdd(&((float*)outv)[(long)row * N + col], val);
                    continue;
                }
                float val = acc[i][j][rr] + bv;
                if (MODE == 0) {
                    val += res[(long)row * N + col];
                    ((float*)outv)[(long)row * N + col] = val;
                } else if (MODE == 1) {
                    val = fmaxf(val, 0.f);
                    ((u16*)outv)[(long)row * N + col] = f2bf(val);
                } else {
                    int which = col >= 1536 ? 2 : (col >= 768 ? 1 : 0);
                    int rem = col - which * 768;
                    int h = rem / 48, d = rem - h * 48;
                    if (which == 0) val *= 0.14433756729740643f;
                    int b = row / SMAXT, s = row - b * SMAXT;
                    ((float*)outv)[(long)which * QKVPLANE + ((long)(b * 16 + h) * SMAXT + s) * 48 + d] = val;
                }
            }
        }
    }
}

// ---------------------------------------------------------------- row-wise QKV projection for 4 rows (one per batch)
__launch_bounds__(256)
__global__ void qkv_update(const u16* __restrict__ h, long hstride, const u16* __restrict__ Wt,
                           const float* __restrict__ bias, float* __restrict__ qkvdst, int srow)
{
    int b = blockIdx.y;
    int col = blockIdx.x * 256 + threadIdx.x;
    __shared__ float hs[768];
    for (int i = threadIdx.x; i < 768; i += 256)
        hs[i] = bf2f(h[(long)b * hstride + i]);
    __syncthreads();
    const short8* wr = (const short8*)(Wt + (long)col * 768);
    float a0 = 0.f, a1 = 0.f, a2 = 0.f, a3 = 0.f;
    #pragma unroll 4
    for (int k8 = 0; k8 < 96; ++k8) {
        short8 wv = wr[k8];
        const float* hp = &hs[k8 * 8];
        a0 = fmaf(hp[0], bf2f((u16)wv[0]), a0);
        a1 = fmaf(hp[1], bf2f((u16)wv[1]), a1);
        a2 = fmaf(hp[2], bf2f((u16)wv[2]), a2);
        a3 = fmaf(hp[3], bf2f((u16)wv[3]), a3);
        a0 = fmaf(hp[4], bf2f((u16)wv[4]), a0);
        a1 = fmaf(hp[5], bf2f((u16)wv[5]), a1);
        a2 = fmaf(hp[6], bf2f((u16)wv[6]), a2);
        a3 = fmaf(hp[7], bf2f((u16)wv[7]), a3);
    }
    float acc = (a0 + a1) + (a2 + a3) + bias[col];
    int which = col >= 1536 ? 2 : (col >= 768 ? 1 : 0);
    int rem = col - which * 768;
    int hh = rem / 48, d = rem - hh * 48;
    if (which == 0) acc *= 0.14433756729740643f;
    qkvdst[(long)which * QKVPLANE + ((long)(b * 16 + hh) * SMAXT + srow) * 48 + d] = acc;
}

// ---------------------------------------------------------------- attention (fp32, head-major qkv, q pre-scaled)
__launch_bounds__(256)
__global__ void attn_kernel(const float* __restrict__ qkv, u16* __restrict__ o, int S,
                            float* __restrict__ state, int q0base)
{
    int bh = blockIdx.y;                 // b*16 + h
    int b = bh >> 4, h = bh & 15;
    int q0 = q0base + blockIdx.x * 16;
    if (q0 >= S) return;
    __shared__ float qs[16][48];
    __shared__ float kbuf[3328];         // Ks[64][52] OR VsT[48][68]
    __shared__ float sc[16][304];
    int t = threadIdx.x;
    const float* qp = qkv + (long)bh * SMAXT * 48;
    const float* kp = qp + QKVPLANE;
    const float* vp = qp + 2 * QKVPLANE;

    for (int lin = t; lin < 16 * 48; lin += 256) {
        int i2 = lin / 48, d = lin % 48;
        int qi2 = q0 + i2; if (qi2 > S - 1) qi2 = S - 1;
        qs[i2][d] = qp[(long)qi2 * 48 + d];
    }
    __syncthreads();
    int i = t >> 4, j = t & 15;
    int qi = q0 + i;
    float4 q4[12];
    #pragma unroll
    for (int k4 = 0; k4 < 12; ++k4) q4[k4] = *(const float4*)&qs[i][k4 * 4];

    // ---- scores
    for (int s0 = 0; s0 < S; s0 += 64) {
        int ns = S - s0; if (ns > 64) ns = 64;
        __syncthreads();
        for (int lin = t; lin < 64 * 12; lin += 256) {
            int ss = lin / 12, d4 = lin % 12;
            float4 kv = make_float4(0.f, 0.f, 0.f, 0.f);
            if (ss < ns) kv = *(const float4*)(kp + (long)(s0 + ss) * 48 + d4 * 4);
            *(float4*)&kbuf[ss * 52 + d4 * 4] = kv;
        }
        __syncthreads();
        #pragma unroll
        for (int u = 0; u < 4; ++u) {
            int ss = j + 16 * u;
            float acc = 0.f;
            #pragma unroll
            for (int k4 = 0; k4 < 12; ++k4) {
                float4 kk = *(const float4*)&kbuf[ss * 52 + k4 * 4];
                acc += q4[k4].x * kk.x + q4[k4].y * kk.y + q4[k4].z * kk.z + q4[k4].w * kk.w;
            }
            int s = s0 + ss;
            if (ss < ns) {
                bool masked = (qi >= CCTX) && (s > qi);
                sc[i][s] = masked ? acc + NEGV : acc;
            }
        }
    }
    __syncthreads();

    // ---- softmax
    float mx = -1e30f;
    for (int s = j; s < S; s += 16) mx = fmaxf(mx, sc[i][s]);
    #pragma unroll
    for (int m = 8; m; m >>= 1) mx = fmaxf(mx, __shfl_xor(mx, m, 16));
    int Sp = (S + 3) & ~3;
    float sum = 0.f;
    for (int s = j; s < Sp; s += 16) {
        float e = (s < S) ? __expf(sc[i][s] - mx) : 0.f;
        sc[i][s] = e; sum += e;
    }
    #pragma unroll
    for (int m = 8; m; m >>= 1) sum += __shfl_xor(sum, m, 16);
    float inv = 1.f / sum;

    // ---- o = softmax @ V
    float oc0 = 0.f, oc1 = 0.f, oc2 = 0.f;
    int d0 = j * 3;
    for (int s0 = 0; s0 < S; s0 += 64) {
        int ns4 = Sp - s0; if (ns4 > 64) ns4 = 64;
        __syncthreads();
        for (int lin = t; lin < 64 * 48; lin += 256) {
            int ss = lin / 48, d = lin % 48;
            float v = 0.f;
            int s = s0 + ss;
            if (s < S) v = vp[(long)s * 48 + d];
            kbuf[d * 68 + ss] = v;
        }
        __syncthreads();
        for (int sb = 0; sb < ns4; sb += 4) {
            float4 a4 = *(const float4*)&sc[i][s0 + sb];
            float4 v0 = *(const float4*)&kbuf[d0 * 68 + sb];
            float4 v1 = *(const float4*)&kbuf[(d0 + 1) * 68 + sb];
            float4 v2 = *(const float4*)&kbuf[(d0 + 2) * 68 + sb];
            oc0 += a4.x * v0.x + a4.y * v0.y + a4.z * v0.z + a4.w * v0.w;
            oc1 += a4.x * v1.x + a4.y * v1.y + a4.z * v1.z + a4.w * v1.w;
            oc2 += a4.x * v2.x + a4.y * v2.y + a4.z * v2.z + a4.w * v2.w;
        }
    }
    if (qi < S) {
        u16* orow = o + ((long)(b * SMAXT + qi)) * 768 + h * 48 + d0;
        orow[0] = f2bf(oc0 * inv); orow[1] = f2bf(oc1 * inv); orow[2] = f2bf(oc2 * inv);
    }
    if (state && qi < CCTX) {
        float* st = state + ((long)bh * 293 + qi) * STSTRIDE;
        st[d0] = oc0; st[d0 + 1] = oc1; st[d0 + 2] = oc2;
        if (j == 0) { st[48] = mx; st[49] = sum; }
    }
}

// ---------------------------------------------------------------- layer-0 incremental attention (t>=1)
__launch_bounds__(256)
__global__ void attn0_inc(const float* __restrict__ qkv, float* __restrict__ state,
                          u16* __restrict__ o, int S)
{
    int bh = blockIdx.x & 63;
    int b = bh >> 4, h = bh & 15;
    int t = threadIdx.x;
    const float* qp = qkv + (long)bh * SMAXT * 48;
    const float* kp = qp + QKVPLANE;
    const float* vp = qp + 2 * QKVPLANE;
    __shared__ float buf[304];
    __shared__ float kn[48], vn[48];
    __shared__ float redm[4], redl[4];

    if (blockIdx.x < 64) {
        if (t < 48) kn[t] = kp[(long)(S - 1) * 48 + t];
        else if (t < 96) vn[t - 48] = vp[(long)(S - 1) * 48 + (t - 48)];
        __syncthreads();
        for (int r = t; r < CCTX; r += 256) {
            const float* qr = qp + (long)r * 48;
            float x = 0.f;
            #pragma unroll
            for (int d = 0; d < 48; ++d) x += qr[d] * kn[d];
            float* st = state + ((long)bh * 293 + r) * STSTRIDE;
            float m_old = st[48], l_old = st[49];
            float m_new = fmaxf(m_old, x);
            float f = __expf(m_old - m_new), e = __expf(x - m_new);
            float l_new = l_old * f + e;
            st[48] = m_new; st[49] = l_new;
            float invl = 1.f / l_new;
            u16* orow = o + ((long)(b * SMAXT + r)) * 768 + h * 48;
            #pragma unroll
            for (int d = 0; d < 48; ++d) {
                float oa = st[d] * f + e * vn[d];
                st[d] = oa;
                orow[d] = f2bf(oa * invl);
            }
        }
    } else {
        if (t < 48) kn[t] = qp[(long)(S - 1) * 48 + t];   // kn reused as q row
        __syncthreads();
        float mymax = -1e30f;
        for (int s = t; s < S; s += 256) {
            const float* kr = kp + (long)s * 48;
            float x = 0.f;
            #pragma unroll
            for (int d = 0; d < 48; ++d) x += kn[d] * kr[d];
            buf[s] = x;
            mymax = fmaxf(mymax, x);
        }
        for (int off = 32; off; off >>= 1) mymax = fmaxf(mymax, __shfl_down(mymax, off, 64));
        int wid = t >> 6, lane = t & 63;
        if (!lane) redm[wid] = mymax;
        __syncthreads();
        float mx = fmaxf(fmaxf(redm[0], redm[1]), fmaxf(redm[2], redm[3]));
        float lsum = 0.f;
        for (int s = t; s < S; s += 256) {
            float e = __expf(buf[s] - mx);
            buf[s] = e; lsum += e;
        }
        for (int off = 32; off; off >>= 1) lsum += __shfl_down(lsum, off, 64);
        if (!lane) redl[wid] = lsum;
        __syncthreads();
        float inv = 1.f / (redl[0] + redl[1] + redl[2] + redl[3]);
        if (t < 48) {
            float acc = 0.f;
            for (int s = 0; s < S; ++s) acc += buf[s] * vp[(long)s * 48 + t];
            u16* orow = o + ((long)(b * SMAXT + (S - 1))) * 768 + h * 48;
            orow[t] = f2bf(acc * inv);
        }
    }
}

// ---------------------------------------------------------------- layer-2 tiny O-proj (+residual), 4 rows
__launch_bounds__(256)
__global__ void otiny_kernel(const u16* __restrict__ ao, const u16* __restrict__ WoT2,
                             const float* __restrict__ bo2, float* __restrict__ xbuf, int S)
{
    int b = blockIdx.y;
    int col = blockIdx.x * 256 + threadIdx.x;
    long row = (long)b * SMAXT + (S - 1);
    __shared__ float hs[768];
    for (int i = threadIdx.x; i < 768; i += 256) hs[i] = bf2f(ao[row * 768 + i]);
    __syncthreads();
    const short8* wr = (const short8*)(WoT2 + (long)col * 768);
    float a0 = 0.f, a1 = 0.f, a2 = 0.f, a3 = 0.f;
    #pragma unroll 4
    for (int k8 = 0; k8 < 96; ++k8) {
        short8 wv = wr[k8];
        const float* hp = &hs[k8 * 8];
        a0 = fmaf(hp[0], bf2f((u16)wv[0]), a0);
        a1 = fmaf(hp[1], bf2f((u16)wv[1]), a1);
        a2 = fmaf(hp[2], bf2f((u16)wv[2]), a2);
        a3 = fmaf(hp[3], bf2f((u16)wv[3]), a3);
        a0 = fmaf(hp[4], bf2f((u16)wv[4]), a0);
        a1 = fmaf(hp[5], bf2f((u16)wv[5]), a1);
        a2 = fmaf(hp[6], bf2f((u16)wv[6]), a2);
        a3 = fmaf(hp[7], bf2f((u16)wv[7]), a3);
    }
    xbuf[row * 768 + col] += (a0 + a1) + (a2 + a3) + bo2[col];
}

// ---------------------------------------------------------------- layer-2 tiny FFN1 (relu -> bf16), 4 rows
__launch_bounds__(256)
__global__ void ffn1_tiny(const u16* __restrict__ h, const u16* __restrict__ W1T2,
                          const float* __restrict__ bf12, u16* __restrict__ big, int S)
{
    int b = blockIdx.y;
    int col = blockIdx.x * 256 + threadIdx.x;   // 0..3071
    long row = (long)b * SMAXT + (S - 1);
    __shared__ float hs[768];
    for (int i = threadIdx.x; i < 768; i += 256) hs[i] = bf2f(h[row * 768 + i]);
    __syncthreads();
    const short8* wr = (const short8*)(W1T2 + (long)col * 768);
    float a0 = 0.f, a1 = 0.f, a2 = 0.f, a3 = 0.f;
    #pragma unroll 4
    for (int k8 = 0; k8 < 96; ++k8) {
        short8 wv = wr[k8];
        const float* hp = &hs[k8 * 8];
        a0 = fmaf(hp[0], bf2f((u16)wv[0]), a0);
        a1 = fmaf(hp[1], bf2f((u16)wv[1]), a1);
        a2 = fmaf(hp[2], bf2f((u16)wv[2]), a2);
        a3 = fmaf(hp[3], bf2f((u16)wv[3]), a3);
        a0 = fmaf(hp[4], bf2f((u16)wv[4]), a0);
        a1 = fmaf(hp[5], bf2f((u16)wv[5]), a1);
        a2 = fmaf(hp[6], bf2f((u16)wv[6]), a2);
        a3 = fmaf(hp[7], bf2f((u16)wv[7]), a3);
    }
    float acc = (a0 + a1) + (a2 + a3) + bf12[col];
    big[row * 3072 + col] = f2bf(fmaxf(acc, 0.f));
}

// ---------------------------------------------------------------- layer-2 tiny FFN2 (+residual), 4 rows
__launch_bounds__(256)
__global__ void ffn2_tiny(const u16* __restrict__ big, const u16* __restrict__ W2T2,
                          const float* __restrict__ bf22, float* __restrict__ xbuf, int S)
{
    int b = blockIdx.y;
    int tid = threadIdx.x;
    int col = blockIdx.x * 64 + (tid & 63);
    int kg = tid >> 6;
    long row = (long)b * SMAXT + (S - 1);
    __shared__ float hs[3072];
    __shared__ float red[4][64];
    for (int i = tid; i < 3072; i += 256) hs[i] = bf2f(big[row * 3072 + i]);
    __syncthreads();
    const short8* wr = (const short8*)(W2T2 + (long)col * 3072 + kg * 768);
    const float* hp0 = &hs[kg * 768];
    float a0 = 0.f, a1 = 0.f, a2 = 0.f, a3 = 0.f;
    #pragma unroll 4
    for (int k8 = 0; k8 < 96; ++k8) {
        short8 wv = wr[k8];
        const float* hp = hp0 + k8 * 8;
        a0 = fmaf(hp[0], bf2f((u16)wv[0]), a0);
        a1 = fmaf(hp[1], bf2f((u16)wv[1]), a1);
        a2 = fmaf(hp[2], bf2f((u16)wv[2]), a2);
        a3 = fmaf(hp[3], bf2f((u16)wv[3]), a3);
        a0 = fmaf(hp[4], bf2f((u16)wv[4]), a0);
        a1 = fmaf(hp[5], bf2f((u16)wv[5]), a1);
        a2 = fmaf(hp[6], bf2f((u16)wv[6]), a2);
        a3 = fmaf(hp[7], bf2f((u16)wv[7]), a3);
    }
    red[kg][tid & 63] = (a0 + a1) + (a2 + a3);
    __syncthreads();
    if (kg == 0) {
        float acc = red[0][tid] + red[1][tid] + red[2][tid] + red[3][tid] + bf22[col];
        xbuf[row * 768 + col] += acc;
    }
}

// ---------------------------------------------------------------- decoder gelu GEMM (4x768 @ 768x768), fp32
__launch_bounds__(256)
__global__ void dec_gelu(const float* __restrict__ src, long srowstride,
                         const float* __restrict__ W, const float* __restrict__ bias,
                         float* __restrict__ dst)
{
    int b = blockIdx.y;
    int jb = blockIdx.x;
    __shared__ float s0buf[768];
    __shared__ float red[4][64];
    int tid = threadIdx.x;
    const float* sr = src + (long)b * srowstride;
    for (int i = tid; i < 768; i += 256) s0buf[i] = sr[i];
    __syncthreads();
    int jj = tid & 63, ig = tid >> 6;
    int jcol = jb * 64 + jj;
    float acc = 0.f;
    const float* wp = W + (long)(ig * 192) * 768 + jcol;
    #pragma unroll 4
    for (int i = 0; i < 192; ++i) acc += s0buf[ig * 192 + i] * wp[(long)i * 768];
    red[ig][jj] = acc;
    __syncthreads();
    if (ig == 0) {
        float a = red[0][jj] + red[1][jj] + red[2][jj] + red[3][jj] + bias[jcol];
        dst[(long)b * 768 + jcol] = gelu_f(a);
    }
}

// ---------------------------------------------------------------- decoder final (+ h0new = ln1(updated Xb row))
__launch_bounds__(256)
__global__ void dec_final(const float* __restrict__ d2, const float* __restrict__ Wd3,
                          const float* __restrict__ bd3, const float* __restrict__ Wpp,
                          const float* __restrict__ bpp, const float* __restrict__ gpp,
                          const float* __restrict__ bepp, float* __restrict__ out,
                          float* __restrict__ X, int t,
                          const float* __restrict__ g1l0, const float* __restrict__ be1l0,
                          u16* __restrict__ h0new)
{
    int b = blockIdx.x;
    int tid = threadIdx.x;
    __shared__ float red[2][4];
    __shared__ float pp[2];
    const float* dr = d2 + (long)b * 768;
    float a0 = 0.f, a1 = 0.f;
    for (int i = tid; i < 768; i += 256) {
        float v = dr[i];
        a0 += v * Wd3[2 * i]; a1 += v * Wd3[2 * i + 1];
    }
    for (int off = 32; off; off >>= 1) { a0 += __shfl_down(a0, off, 64); a1 += __shfl_down(a1, off, 64); }
    int wid = tid >> 6, lane = tid & 63;
    if (!lane) { red[0][wid] = a0; red[1][wid] = a1; }
    __syncthreads();
    if (!tid) {
        float p0 = red[0][0] + red[0][1] + red[0][2] + red[0][3] + bd3[0];
        float p1 = red[1][0] + red[1][1] + red[1][2] + red[1][3] + bd3[1];
        out[(long)(b * NFUT + t) * 2 + 0] = p0;
        out[(long)(b * NFUT + t) * 2 + 1] = p1;
        pp[0] = p0; pp[1] = p1;
    }
    __syncthreads();
    if (t == NFUT - 1) return;
    float p0 = pp[0], p1 = pp[1];
    float pv[3]; float s = 0.f;
    #pragma unroll
    for (int u = 0; u < 3; ++u) {
        int jcol = tid + 256 * u;
        pv[u] = p0 * Wpp[jcol] + p1 * Wpp[768 + jcol] + bpp[jcol];
        s += pv[u];
    }
    for (int off = 32; off; off >>= 1) s += __shfl_down(s, off, 64);
    __syncthreads();
    if (!lane) red[0][wid] = s;
    __syncthreads();
    float mean = (red[0][0] + red[0][1] + red[0][2] + red[0][3]) * (1.f / 768.f);
    float vs = 0.f;
    #pragma unroll
    for (int u = 0; u < 3; ++u) { float d = pv[u] - mean; vs += d * d; }
    for (int off = 32; off; off >>= 1) vs += __shfl_down(vs, off, 64);
    __syncthreads();
    if (!lane) red[1][wid] = vs;
    __syncthreads();
    float var = (red[1][0] + red[1][1] + red[1][2] + red[1][3]) * (1.f / 768.f);
    float inv = rsqrtf(var + 1e-5f);
    float* Xr = X + ((long)(b * SMAXT + CCTX + t + 1)) * 768;
    float xv[3];
    #pragma unroll
    for (int u = 0; u < 3; ++u) {
        int jcol = tid + 256 * u;
        float y = (pv[u] - mean) * inv * gpp[jcol] + bepp[jcol];
        float old = Xr[jcol];
        float nv = old + (y > 0.f ? y : 0.f);
        Xr[jcol] = nv;
        xv[u] = nv;
    }
    float xs = xv[0] + xv[1] + xv[2];
    for (int off = 32; off; off >>= 1) xs += __shfl_down(xs, off, 64);
    __syncthreads();
    if (!lane) red[0][wid] = xs;
    __syncthreads();
    float xmean = (red[0][0] + red[0][1] + red[0][2] + red[0][3]) * (1.f / 768.f);
    float xq = 0.f;
    #pragma unroll
    for (int u = 0; u < 3; ++u) { float d = xv[u] - xmean; xq += d * d; }
    for (int off = 32; off; off >>= 1) xq += __shfl_down(xq, off, 64);
    __syncthreads();
    if (!lane) red[1][wid] = xq;
    __syncthreads();
    float xvar = (red[1][0] + red[1][1] + red[1][2] + red[1][3]) * (1.f / 768.f);
    float xinv = rsqrtf(xvar + 1e-5f);
    #pragma unroll
    for (int u = 0; u < 3; ++u) {
        int jcol = tid + 256 * u;
        h0new[b * 768 + jcol] = f2bf((xv[u] - xmean) * xinv * g1l0[jcol] + be1l0[jcol]);
    }
}

// ---------------------------------------------------------------- launch
extern "C" void kernel_launch(void* const* d_in, const int* in_sizes, int n_in,
                              void* d_out, int out_size, void* d_ws, size_t ws_size,
                              hipStream_t stream)
{
    const float* img    = (const float*)d_in[0];
    const float* past   = (const float*)d_in[1];
    const int*   intent = (const int*)d_in[2];
    const float* pos    = (const float*)d_in[3];
    const float* futq   = (const float*)d_in[4];
    const float* iemb   = (const float*)d_in[5];
    const float* temb   = (const float*)d_in[6];
    const float* W_past = (const float*)d_in[7];
    const float* b_past = (const float*)d_in[8];
    const float* W_ppos = (const float*)d_in[9];
    const float* b_ppos = (const float*)d_in[10];
    const float* W_pp   = (const float*)d_in[11];
    const float* b_pp   = (const float*)d_in[12];
    const float* g_pp   = (const float*)d_in[13];
    const float* be_pp  = (const float*)d_in[14];
    const float* Wqkv   = (const float*)d_in[15];
    const float* bqkv   = (const float*)d_in[16];
    const float* Wo     = (const float*)d_in[17];
    const float* bo     = (const float*)d_in[18];
    const float* g1     = (const float*)d_in[19];
    const float* beta1  = (const float*)d_in[20];
    const float* g2     = (const float*)d_in[21];
    const float* beta2  = (const float*)d_in[22];
    const float* W1     = (const float*)d_in[23];
    const float* bf1    = (const float*)d_in[24];
    const float* W2     = (const float*)d_in[25];
    const float* bf2    = (const float*)d_in[26];
    const float* Wd1    = (const float*)d_in[27];
    const float* bd1    = (const float*)d_in[28];
    const float* Wd2    = (const float*)d_in[29];
    const float* bd2    = (const float*)d_in[30];
    const float* Wd3    = (const float*)d_in[31];
    const float* bd3    = (const float*)d_in[32];
    float* out = (float*)d_out;

    float* ws     = (float*)d_ws;
    float* Xb     = ws;                      // 900096 f
    float* xbuf   = ws + 900096;             // 900096 f
    float* qkvbuf = ws + 1800192;            // 2700288 f (layers 1-2, transient)
    u16*   hbuf   = (u16*)(ws + 4500480);    // 900096 bf16
    u16*   aobuf  = (u16*)(ws + 4950528);    // 900096 bf16 (layers 1-2)
    u16*   big    = (u16*)(ws + 5400576);    // 1172*3072 bf16
    float* d1ws   = ws + 7200768;            // 3072 f
    float* d2ws   = ws + 7203840;            // 3072 f
    u16*   WqkvT  = (u16*)(ws + 7206912);    // 3*2304*768 bf16
    u16*   WoT    = (u16*)(ws + 9861120);    // 3*768*768
    u16*   W1T    = (u16*)(ws + 10745856);   // 3*3072*768
    u16*   W2T    = (u16*)(ws + 14284800);   // 3*768*3072 (ends 17823744)
    float* qkv0   = ws + 17823744;           // 2700288 f (layer-0 persistent qkv)
    u16*   h0new  = (u16*)(ws + 20524032);   // 4*768 bf16 = 1536 f
    u16*   aobuf0 = (u16*)(ws + 20525568);   // 900096 bf16 = 450048 f (layer-0 persistent attn out)
    float* state  = ws + 20975616;           // 64*293*52 = 975104 f (layer-0 softmax state)

    // one-time per launch: weights -> bf16 [N,K]
    convert_transpose<<<dim3(2304/32, 768/32, 3), 256, 0, stream>>>(Wqkv, WqkvT, 768, 2304);
    convert_transpose<<<dim3(768/32, 768/32, 3), 256, 0, stream>>>(Wo, WoT, 768, 768);
    convert_transpose<<<dim3(3072/32, 768/32, 3), 256, 0, stream>>>(W1, W1T, 768, 3072);
    convert_transpose<<<dim3(768/32, 3072/32, 3), 256, 0, stream>>>(W2, W2T, 3072, 768);

    init_base<<<dim3(MROWS), dim3(256), 0, stream>>>(img, past, intent, pos, futq, iemb,
                                                     temb, W_past, b_past, W_ppos, b_ppos, Xb);

    for (int t = 0; t < NFUT; ++t) {
        int S = CCTX + t + 1;

        // ---------------- layer 0 (incremental QKV + incremental attention)
        if (t == 0) {
            ln_kernel<<<dim3(293), dim3(256), 0, stream>>>(Xb, g1, beta1, hbuf);
            gemm_mfma<64, 64, 2, false, 1><<<dim3(36, 19), dim3(256), 0, stream>>>(
                hbuf, nullptr, nullptr, nullptr, WqkvT, bqkv, nullptr, qkv0, MROWS, 2304, 768, 0);
            attn_kernel<<<dim3((S + 15) / 16, 64), dim3(256), 0, stream>>>(qkv0, aobuf0, S, state, 0);
        } else {
            qkv_update<<<dim3(9, 4), dim3(256), 0, stream>>>(h0new, 768L, WqkvT, bqkv, qkv0, CCTX + t);
            attn0_inc<<<dim3(128), dim3(256), 0, stream>>>(qkv0, state, aobuf0, S);
        }
        gemm_mfma<64, 32, 0, false, 1><<<dim3(24, 19), dim3(256), 0, stream>>>(
            aobuf0, nullptr, nullptr, nullptr, WoT, bo, Xb, xbuf, MROWS, 768, 768, 0);
        gemm_mfma<64, 64, 1, true, 1><<<dim3(48, 19), dim3(256), 0, stream>>>(   // LN(g2,l0) fused
            nullptr, xbuf, g2, beta2, W1T, bf1, nullptr, big, MROWS, 3072, 768, 0);
        gemm_mfma<64, 32, 3, false, 4><<<dim3(24, 19, 4), dim3(256), 0, stream>>>( // split-K atomic
            big, nullptr, nullptr, nullptr, W2T, bf2, nullptr, xbuf, MROWS, 768, 3072, 0);

        // ---------------- layer 1 (full)
        gemm_mfma<64, 64, 2, true, 1><<<dim3(36, 19), dim3(256), 0, stream>>>(   // LN(g1,l1) fused
            nullptr, xbuf, g1 + 768, beta1 + 768, WqkvT + 1L * 768 * 2304, bqkv + 2304,
            nullptr, qkvbuf, MROWS, 2304, 768, 0);
        attn_kernel<<<dim3((S + 15) / 16, 64), dim3(256), 0, stream>>>(qkvbuf, aobuf, S, nullptr, 0);
        gemm_mfma<64, 32, 0, false, 1><<<dim3(24, 19), dim3(256), 0, stream>>>(
            aobuf, nullptr, nullptr, nullptr, WoT + 1L * 768 * 768, bo + 768, xbuf, xbuf, MROWS, 768, 768, 0);
        gemm_mfma<64, 64, 1, true, 1><<<dim3(48, 19), dim3(256), 0, stream>>>(   // LN(g2,l1) fused
            nullptr, xbuf, g2 + 768, beta2 + 768, W1T + 1L * 768 * 3072, bf1 + 3072,
            nullptr, big, MROWS, 3072, 768, 0);
        gemm_mfma<64, 32, 3, false, 4><<<dim3(24, 19, 4), dim3(256), 0, stream>>>( // split-K atomic
            big, nullptr, nullptr, nullptr, W2T + 1L * 3072 * 768, bf2 + 768, nullptr, xbuf, MROWS, 768, 3072, 0);

        // ---------------- layer 2 (K/V full, everything else only row S-1)
        gemm_mfma<64, 32, 2, true, 1><<<dim3(48, 19), dim3(256), 0, stream>>>(   // LN(g1,l2) fused; K,V cols
            nullptr, xbuf, g1 + 2 * 768, beta1 + 2 * 768, WqkvT + 2L * 768 * 2304, bqkv + 2 * 2304,
            nullptr, qkvbuf, MROWS, 2304, 768, 768);
        ln4_kernel<<<dim3(1), dim3(256), 0, stream>>>(xbuf, g1 + 2 * 768, beta1 + 2 * 768, hbuf, S);
        qkv_update<<<dim3(3, 4), dim3(256), 0, stream>>>(                        // Q row S-1 (cols 0..767)
            hbuf + (long)(S - 1) * 768, (long)SMAXT * 768,
            WqkvT + 2L * 768 * 2304, bqkv + 2 * 2304, qkvbuf, S - 1);
        attn_kernel<<<dim3(1, 64), dim3(256), 0, stream>>>(qkvbuf, aobuf, S, nullptr, S - 16);
        otiny_kernel<<<dim3(3, 4), dim3(256), 0, stream>>>(aobuf, WoT + 2L * 768 * 768, bo + 2 * 768, xbuf, S);
        ln4_kernel<<<dim3(1), dim3(256), 0, stream>>>(xbuf, g2 + 2 * 768, beta2 + 2 * 768, hbuf, S);
        ffn1_tiny<<<dim3(12, 4), dim3(256), 0, stream>>>(hbuf, W1T + 2L * 768 * 3072, bf1 + 2 * 3072, big, S);
        ffn2_tiny<<<dim3(12, 4), dim3(256), 0, stream>>>(big, W2T + 2L * 3072 * 768, bf2 + 2 * 768, xbuf, S);

        // ---------------- decoder
        dec_gelu<<<dim3(12, 4), dim3(256), 0, stream>>>(xbuf + (long)(S - 1) * 768, (long)SMAXT * 768, Wd1, bd1, d1ws);
        dec_gelu<<<dim3(12, 4), dim3(256), 0, stream>>>(d1ws, 768L, Wd2, bd2, d2ws);
        dec_final<<<dim3(4), dim3(256), 0, stream>>>(d2ws, Wd3, bd3, W_pp, b_pp, g_pp, be_pp, out, Xb, t,
                                                     g1, beta1, h0new);
    }
}

// Round 9
// 9050.883 us; speedup vs baseline: 1.1418x; 1.1418x over previous
//
#include <hip/hip_runtime.h>
#include <math.h>

#define DIM   768
#define NHEAD 16
#define DHEAD 48
#define NLAY  3
#define NTOK  256
#define BATCH 4
#define NPAST_ 16
#define NFUT  20
#define CCTX  273              // NTOK + 1 + NPAST
#define SMAXT 293              // CCTX + NFUT
#define MROWS 1172             // BATCH * SMAXT
#define NEGV  (-1.0e9f)
#define QKVPLANE 900096        // BATCH*NHEAD*SMAXT*48
#define STSTRIDE 52            // per-row softmax state: 48 oacc + m + l (+pad)

typedef unsigned short u16;
typedef unsigned int   u32;
typedef __attribute__((ext_vector_type(8))) short short8;
typedef __attribute__((ext_vector_type(4))) float floatx4;

__device__ inline u16 f2bf(float x) {
    union { float f; u32 u; } v; v.f = x;
    u32 r = v.u + 0x7fffu + ((v.u >> 16) & 1u);
    return (u16)(r >> 16);
}

__device__ inline float bf2f(u16 x) {
    union { u32 u; float f; } c; c.u = ((u32)x) << 16;
    return c.f;
}

__device__ inline float gelu_f(float x) {
    return 0.5f * x * (1.0f + erff(x * 0.70710678118654752f));
}

// ---------------------------------------------------------------- init X_base
__global__ void init_base(const float* __restrict__ img, const float* __restrict__ past,
                          const int* __restrict__ intent, const float* __restrict__ pos,
                          const float* __restrict__ futq, const float* __restrict__ iemb,
                          const float* __restrict__ temb, const float* __restrict__ Wp,
                          const float* __restrict__ bp, const float* __restrict__ Wpp,
                          const float* __restrict__ bpp, float* __restrict__ X)
{
    int r = blockIdx.x;
    int b = r / SMAXT, s = r % SMAXT;
    for (int j = threadIdx.x; j < DIM; j += blockDim.x) {
        float v;
        if (s < NTOK) {
            v = img[(long)(b * NTOK + s) * DIM + j] + pos[(long)s * DIM + j];
        } else if (s == NTOK) {
            int idx = intent[b] - 1; idx = idx < 0 ? 0 : (idx > 2 ? 2 : idx);
            v = iemb[(long)idx * DIM + j];
        } else if (s < CCTX) {
            int i = s - (NTOK + 1);
            v = bp[j] + bpp[j] + temb[(long)i * DIM + j];
            const float* pr = past + (long)(b * NPAST_ + i) * 6;
            #pragma unroll
            for (int c = 0; c < 6; ++c) v += pr[c] * Wp[(long)c * DIM + j];
            v += pr[0] * Wpp[j] + pr[1] * Wpp[DIM + j];
        } else {
            int f = s - CCTX;
            v = futq[(long)f * DIM + j] + temb[(long)(NPAST_ + f) * DIM + j];
        }
        X[(long)r * DIM + j] = v;
    }
}

// ---------------------------------------------------------------- weight convert + transpose: W[K,N] fp32 -> Wt[N,K] bf16
__global__ void convert_transpose(const float* __restrict__ W, u16* __restrict__ Wt, int K, int N)
{
    __shared__ float tile[32][33];
    long lstride = (long)K * N;
    W  += blockIdx.z * lstride;
    Wt += blockIdx.z * lstride;
    int n0 = blockIdx.x * 32, k0 = blockIdx.y * 32;
    int tx = threadIdx.x & 31, ty = threadIdx.x >> 5;
    for (int i = ty; i < 32; i += 8)
        tile[i][tx] = W[(long)(k0 + i) * N + n0 + tx];
    __syncthreads();
    for (int i = ty; i < 32; i += 8)
        Wt[(long)(n0 + i) * K + k0 + tx] = f2bf(tile[tx][i]);
}

// ---------------------------------------------------------------- layernorm -> bf16 (all rows)
__launch_bounds__(256)
__global__ void ln_kernel(const float* __restrict__ x, const float* __restrict__ g,
                          const float* __restrict__ be, u16* __restrict__ y)
{
    int row = blockIdx.x * 4 + (threadIdx.x >> 6);
    int lane = threadIdx.x & 63;
    if (row >= MROWS) return;
    const float* xr = x + (long)row * DIM;
    float v[12];
    float s = 0.f;
    #pragma unroll
    for (int i = 0; i < 12; ++i) { v[i] = xr[lane + 64 * i]; s += v[i]; }
    for (int off = 32; off; off >>= 1) s += __shfl_down(s, off, 64);
    s = __shfl(s, 0, 64);
    float mean = s * (1.f / 768.f);
    float vs = 0.f;
    #pragma unroll
    for (int i = 0; i < 12; ++i) { float d = v[i] - mean; vs += d * d; }
    for (int off = 32; off; off >>= 1) vs += __shfl_down(vs, off, 64);
    vs = __shfl(vs, 0, 64);
    float inv = rsqrtf(vs * (1.f / 768.f) + 1e-5f);
    u16* yr = y + (long)row * DIM;
    #pragma unroll
    for (int i = 0; i < 12; ++i) {
        int j = lane + 64 * i;
        yr[j] = f2bf((v[i] - mean) * inv * g[j] + be[j]);
    }
}

// ---------------------------------------------------------------- layernorm of the 4 rows (b*SMAXT + S-1) only
__launch_bounds__(256)
__global__ void ln4_kernel(const float* __restrict__ x, const float* __restrict__ g,
                           const float* __restrict__ be, u16* __restrict__ y, int S)
{
    int b = threadIdx.x >> 6;
    int lane = threadIdx.x & 63;
    long row = (long)b * SMAXT + (S - 1);
    const float* xr = x + row * DIM;
    float v[12];
    float s = 0.f;
    #pragma unroll
    for (int i = 0; i < 12; ++i) { v[i] = xr[lane + 64 * i]; s += v[i]; }
    for (int off = 32; off; off >>= 1) s += __shfl_down(s, off, 64);
    s = __shfl(s, 0, 64);
    float mean = s * (1.f / 768.f);
    float vs = 0.f;
    #pragma unroll
    for (int i = 0; i < 12; ++i) { float d = v[i] - mean; vs += d * d; }
    for (int off = 32; off; off >>= 1) vs += __shfl_down(vs, off, 64);
    vs = __shfl(vs, 0, 64);
    float inv = rsqrtf(vs * (1.f / 768.f) + 1e-5f);
    u16* yr = y + row * DIM;
    #pragma unroll
    for (int i = 0; i < 12; ++i) {
        int j = lane + 64 * i;
        yr[j] = f2bf((v[i] - mean) * inv * g[j] + be[j]);
    }
}

// ---------------------------------------------------------------- bf16 MFMA GEMM (verified structure; optional split-K)
// A[M,K] bf16 row-major, Wt[N,K] bf16 row-major.  C = A @ Wt^T + bias.
// MODE 0: out fp32, += res.  MODE 1: relu, out bf16.  MODE 2: qkv-permuted fp32.
// MODE 3 (KSPLIT>1): atomicAdd into out (residual pre-resident); bias added by kz==0.
// Small tiles maximize grid size (CU-coverage/latency-bound regime, R6/R7).
template<int BM, int BN, int MODE, int KSPLIT>
__launch_bounds__(256)
__global__ void gemm_mfma(const u16* __restrict__ A, const u16* __restrict__ Wt,
                          const float* __restrict__ bias, const float* __restrict__ res,
                          void* __restrict__ outv, int M, int N, int K, int n0base)
{
    constexpr int MFRAG = BM / 16;
    constexpr int MI = MFRAG / 2;
    constexpr int NSUB = BN / 16;
    constexpr int NJ = NSUB / 2;
    constexpr int NA = (BM * 8) / 256;
    constexpr int NB = (BN * 8) / 256;
    __shared__ u16 As[2 * MFRAG * 64 * 8];
    __shared__ u16 Bs[2 * NSUB * 64 * 8];

    int tid = threadIdx.x;
    int lane = tid & 63;
    int w = tid >> 6, wm = w >> 1, wn = w & 1;
    int m0 = blockIdx.y * BM, n0 = n0base + blockIdx.x * BN;

    floatx4 acc[MI][NJ];
    #pragma unroll
    for (int i = 0; i < MI; ++i)
        #pragma unroll
        for (int j = 0; j < NJ; ++j) acc[i][j] = (floatx4){0.f, 0.f, 0.f, 0.f};

    int lm = lane & 15, lk = lane >> 4;      // fragment (m, kgroup)

    int ksz = K / KSPLIT;
    int kb = (KSPLIT > 1) ? blockIdx.z * ksz : 0;
    for (int k0 = kb; k0 < kb + ksz; k0 += 64) {
        __syncthreads();
        #pragma unroll
        for (int i = 0; i < NA; ++i) {       // A: BM rows x 8 chunks
            int q = tid + 256 * i;
            int r = q >> 3, c = q & 7;
            int gr = m0 + r; if (gr >= M) gr = M - 1;
            int4 v = *(const int4*)(A + (long)gr * K + k0 + c * 8);
            int off = (((c >> 2) * MFRAG + (r >> 4)) * 64 + (r & 15) * 4 + (c & 3)) * 8;
            *(int4*)&As[off] = v;
        }
        #pragma unroll
        for (int i = 0; i < NB; ++i) {       // B: BN rows x 8 chunks
            int q = tid + 256 * i;
            int r = q >> 3, c = q & 7;
            int4 v = *(const int4*)(Wt + (long)(n0 + r) * K + k0 + c * 8);
            int off = (((c >> 2) * NSUB + (r >> 4)) * 64 + (r & 15) * 4 + (c & 3)) * 8;
            *(int4*)&Bs[off] = v;
        }
        __syncthreads();
        #pragma unroll
        for (int t = 0; t < 2; ++t) {
            short8 af[MI];
            #pragma unroll
            for (int i = 0; i < MI; ++i)
                af[i] = *(const short8*)&As[((t * MFRAG + wm * MI + i) * 64 + lm * 4 + lk) * 8];
            short8 bfr[NJ];
            #pragma unroll
            for (int j = 0; j < NJ; ++j)
                bfr[j] = *(const short8*)&Bs[((t * NSUB + wn * NJ + j) * 64 + lm * 4 + lk) * 8];
            #pragma unroll
            for (int i = 0; i < MI; ++i)
                #pragma unroll
                for (int j = 0; j < NJ; ++j)
                    acc[i][j] = __builtin_amdgcn_mfma_f32_16x16x32_bf16(af[i], bfr[j], acc[i][j], 0, 0, 0);
        }
    }

    #pragma unroll
    for (int j = 0; j < NJ; ++j) {
        int col = n0 + wn * (NJ * 16) + j * 16 + lm;
        float bv = bias[col];
        #pragma unroll
        for (int i = 0; i < MI; ++i) {
            int rbase = m0 + wm * (MI * 16) + i * 16 + lk * 4;
            #pragma unroll
            for (int rr = 0; rr < 4; ++rr) {
                int row = rbase + rr;
                if (row >= M) continue;
                if (MODE == 3) {
                    float val = acc[i][j][rr] + (blockIdx.z == 0 ? bv : 0.f);
                    atomicAdd(&((float*)outv)[(long)row * N + col], val);
                    continue;
                }
                float val = acc[i][j][rr] + bv;
                if (MODE == 0) {
                    val += res[(long)row * N + col];
                    ((float*)outv)[(long)row * N + col] = val;
                } else if (MODE == 1) {
                    val = fmaxf(val, 0.f);
                    ((u16*)outv)[(long)row * N + col] = f2bf(val);
                } else {
                    int which = col >= 1536 ? 2 : (col >= 768 ? 1 : 0);
                    int rem = col - which * 768;
                    int h = rem / 48, d = rem - h * 48;
                    if (which == 0) val *= 0.14433756729740643f;
                    int b = row / SMAXT, s = row - b * SMAXT;
                    ((float*)outv)[(long)which * QKVPLANE + ((long)(b * 16 + h) * SMAXT + s) * 48 + d] = val;
                }
            }
        }
    }
}

// ---------------------------------------------------------------- row-wise QKV projection for 4 rows (one per batch)
__launch_bounds__(256)
__global__ void qkv_update(const u16* __restrict__ h, long hstride, const u16* __restrict__ Wt,
                           const float* __restrict__ bias, float* __restrict__ qkvdst, int srow)
{
    int b = blockIdx.y;
    int col = blockIdx.x * 256 + threadIdx.x;
    __shared__ float hs[768];
    for (int i = threadIdx.x; i < 768; i += 256)
        hs[i] = bf2f(h[(long)b * hstride + i]);
    __syncthreads();
    const short8* wr = (const short8*)(Wt + (long)col * 768);
    float a0 = 0.f, a1 = 0.f, a2 = 0.f, a3 = 0.f;
    #pragma unroll 4
    for (int k8 = 0; k8 < 96; ++k8) {
        short8 wv = wr[k8];
        const float* hp = &hs[k8 * 8];
        a0 = fmaf(hp[0], bf2f((u16)wv[0]), a0);
        a1 = fmaf(hp[1], bf2f((u16)wv[1]), a1);
        a2 = fmaf(hp[2], bf2f((u16)wv[2]), a2);
        a3 = fmaf(hp[3], bf2f((u16)wv[3]), a3);
        a0 = fmaf(hp[4], bf2f((u16)wv[4]), a0);
        a1 = fmaf(hp[5], bf2f((u16)wv[5]), a1);
        a2 = fmaf(hp[6], bf2f((u16)wv[6]), a2);
        a3 = fmaf(hp[7], bf2f((u16)wv[7]), a3);
    }
    float acc = (a0 + a1) + (a2 + a3) + bias[col];
    int which = col >= 1536 ? 2 : (col >= 768 ? 1 : 0);
    int rem = col - which * 768;
    int hh = rem / 48, d = rem - hh * 48;
    if (which == 0) acc *= 0.14433756729740643f;
    qkvdst[(long)which * QKVPLANE + ((long)(b * 16 + hh) * SMAXT + srow) * 48 + d] = acc;
}

// ---------------------------------------------------------------- attention (fp32, head-major qkv, q pre-scaled)
__launch_bounds__(256)
__global__ void attn_kernel(const float* __restrict__ qkv, u16* __restrict__ o, int S,
                            float* __restrict__ state, int q0base)
{
    int bh = blockIdx.y;                 // b*16 + h
    int b = bh >> 4, h = bh & 15;
    int q0 = q0base + blockIdx.x * 16;
    if (q0 >= S) return;
    __shared__ float qs[16][48];
    __shared__ float kbuf[3328];         // Ks[64][52] OR VsT[48][68]
    __shared__ float sc[16][304];
    int t = threadIdx.x;
    const float* qp = qkv + (long)bh * SMAXT * 48;
    const float* kp = qp + QKVPLANE;
    const float* vp = qp + 2 * QKVPLANE;

    for (int lin = t; lin < 16 * 48; lin += 256) {
        int i2 = lin / 48, d = lin % 48;
        int qi2 = q0 + i2; if (qi2 > S - 1) qi2 = S - 1;
        qs[i2][d] = qp[(long)qi2 * 48 + d];
    }
    __syncthreads();
    int i = t >> 4, j = t & 15;
    int qi = q0 + i;
    float4 q4[12];
    #pragma unroll
    for (int k4 = 0; k4 < 12; ++k4) q4[k4] = *(const float4*)&qs[i][k4 * 4];

    // ---- scores
    for (int s0 = 0; s0 < S; s0 += 64) {
        int ns = S - s0; if (ns > 64) ns = 64;
        __syncthreads();
        for (int lin = t; lin < 64 * 12; lin += 256) {
            int ss = lin / 12, d4 = lin % 12;
            float4 kv = make_float4(0.f, 0.f, 0.f, 0.f);
            if (ss < ns) kv = *(const float4*)(kp + (long)(s0 + ss) * 48 + d4 * 4);
            *(float4*)&kbuf[ss * 52 + d4 * 4] = kv;
        }
        __syncthreads();
        #pragma unroll
        for (int u = 0; u < 4; ++u) {
            int ss = j + 16 * u;
            float acc = 0.f;
            #pragma unroll
            for (int k4 = 0; k4 < 12; ++k4) {
                float4 kk = *(const float4*)&kbuf[ss * 52 + k4 * 4];
                acc += q4[k4].x * kk.x + q4[k4].y * kk.y + q4[k4].z * kk.z + q4[k4].w * kk.w;
            }
            int s = s0 + ss;
            if (ss < ns) {
                bool masked = (qi >= CCTX) && (s > qi);
                sc[i][s] = masked ? acc + NEGV : acc;
            }
        }
    }
    __syncthreads();

    // ---- softmax
    float mx = -1e30f;
    for (int s = j; s < S; s += 16) mx = fmaxf(mx, sc[i][s]);
    #pragma unroll
    for (int m = 8; m; m >>= 1) mx = fmaxf(mx, __shfl_xor(mx, m, 16));
    int Sp = (S + 3) & ~3;
    float sum = 0.f;
    for (int s = j; s < Sp; s += 16) {
        float e = (s < S) ? __expf(sc[i][s] - mx) : 0.f;
        sc[i][s] = e; sum += e;
    }
    #pragma unroll
    for (int m = 8; m; m >>= 1) sum += __shfl_xor(sum, m, 16);
    float inv = 1.f / sum;

    // ---- o = softmax @ V
    float oc0 = 0.f, oc1 = 0.f, oc2 = 0.f;
    int d0 = j * 3;
    for (int s0 = 0; s0 < S; s0 += 64) {
        int ns4 = Sp - s0; if (ns4 > 64) ns4 = 64;
        __syncthreads();
        for (int lin = t; lin < 64 * 48; lin += 256) {
            int ss = lin / 48, d = lin % 48;
            float v = 0.f;
            int s = s0 + ss;
            if (s < S) v = vp[(long)s * 48 + d];
            kbuf[d * 68 + ss] = v;
        }
        __syncthreads();
        for (int sb = 0; sb < ns4; sb += 4) {
            float4 a4 = *(const float4*)&sc[i][s0 + sb];
            float4 v0 = *(const float4*)&kbuf[d0 * 68 + sb];
            float4 v1 = *(const float4*)&kbuf[(d0 + 1) * 68 + sb];
            float4 v2 = *(const float4*)&kbuf[(d0 + 2) * 68 + sb];
            oc0 += a4.x * v0.x + a4.y * v0.y + a4.z * v0.z + a4.w * v0.w;
            oc1 += a4.x * v1.x + a4.y * v1.y + a4.z * v1.z + a4.w * v1.w;
            oc2 += a4.x * v2.x + a4.y * v2.y + a4.z * v2.z + a4.w * v2.w;
        }
    }
    if (qi < S) {
        u16* orow = o + ((long)(b * SMAXT + qi)) * 768 + h * 48 + d0;
        orow[0] = f2bf(oc0 * inv); orow[1] = f2bf(oc1 * inv); orow[2] = f2bf(oc2 * inv);
    }
    if (state && qi < CCTX) {
        float* st = state + ((long)bh * 293 + qi) * STSTRIDE;
        st[d0] = oc0; st[d0 + 1] = oc1; st[d0 + 2] = oc2;
        if (j == 0) { st[48] = mx; st[49] = sum; }
    }
}

// ---------------------------------------------------------------- layer-0 incremental attention (t>=1)
__launch_bounds__(256)
__global__ void attn0_inc(const float* __restrict__ qkv, float* __restrict__ state,
                          u16* __restrict__ o, int S)
{
    int bh = blockIdx.x & 63;
    int b = bh >> 4, h = bh & 15;
    int t = threadIdx.x;
    const float* qp = qkv + (long)bh * SMAXT * 48;
    const float* kp = qp + QKVPLANE;
    const float* vp = qp + 2 * QKVPLANE;
    __shared__ float buf[304];
    __shared__ float kn[48], vn[48];
    __shared__ float redm[4], redl[4];

    if (blockIdx.x < 64) {
        if (t < 48) kn[t] = kp[(long)(S - 1) * 48 + t];
        else if (t < 96) vn[t - 48] = vp[(long)(S - 1) * 48 + (t - 48)];
        __syncthreads();
        for (int r = t; r < CCTX; r += 256) {
            const float* qr = qp + (long)r * 48;
            float x = 0.f;
            #pragma unroll
            for (int d = 0; d < 48; ++d) x += qr[d] * kn[d];
            float* st = state + ((long)bh * 293 + r) * STSTRIDE;
            float m_old = st[48], l_old = st[49];
            float m_new = fmaxf(m_old, x);
            float f = __expf(m_old - m_new), e = __expf(x - m_new);
            float l_new = l_old * f + e;
            st[48] = m_new; st[49] = l_new;
            float invl = 1.f / l_new;
            u16* orow = o + ((long)(b * SMAXT + r)) * 768 + h * 48;
            #pragma unroll
            for (int d = 0; d < 48; ++d) {
                float oa = st[d] * f + e * vn[d];
                st[d] = oa;
                orow[d] = f2bf(oa * invl);
            }
        }
    } else {
        if (t < 48) kn[t] = qp[(long)(S - 1) * 48 + t];   // kn reused as q row
        __syncthreads();
        float mymax = -1e30f;
        for (int s = t; s < S; s += 256) {
            const float* kr = kp + (long)s * 48;
            float x = 0.f;
            #pragma unroll
            for (int d = 0; d < 48; ++d) x += kn[d] * kr[d];
            buf[s] = x;
            mymax = fmaxf(mymax, x);
        }
        for (int off = 32; off; off >>= 1) mymax = fmaxf(mymax, __shfl_down(mymax, off, 64));
        int wid = t >> 6, lane = t & 63;
        if (!lane) redm[wid] = mymax;
        __syncthreads();
        float mx = fmaxf(fmaxf(redm[0], redm[1]), fmaxf(redm[2], redm[3]));
        float lsum = 0.f;
        for (int s = t; s < S; s += 256) {
            float e = __expf(buf[s] - mx);
            buf[s] = e; lsum += e;
        }
        for (int off = 32; off; off >>= 1) lsum += __shfl_down(lsum, off, 64);
        if (!lane) redl[wid] = lsum;
        __syncthreads();
        float inv = 1.f / (redl[0] + redl[1] + redl[2] + redl[3]);
        if (t < 48) {
            float acc = 0.f;
            for (int s = 0; s < S; ++s) acc += buf[s] * vp[(long)s * 48 + t];
            u16* orow = o + ((long)(b * SMAXT + (S - 1))) * 768 + h * 48;
            orow[t] = f2bf(acc * inv);
        }
    }
}

// ---------------------------------------------------------------- layer-2 tiny O-proj (+residual), 4 rows
__launch_bounds__(256)
__global__ void otiny_kernel(const u16* __restrict__ ao, const u16* __restrict__ WoT2,
                             const float* __restrict__ bo2, float* __restrict__ xbuf, int S)
{
    int b = blockIdx.y;
    int col = blockIdx.x * 256 + threadIdx.x;
    long row = (long)b * SMAXT + (S - 1);
    __shared__ float hs[768];
    for (int i = threadIdx.x; i < 768; i += 256) hs[i] = bf2f(ao[row * 768 + i]);
    __syncthreads();
    const short8* wr = (const short8*)(WoT2 + (long)col * 768);
    float a0 = 0.f, a1 = 0.f, a2 = 0.f, a3 = 0.f;
    #pragma unroll 4
    for (int k8 = 0; k8 < 96; ++k8) {
        short8 wv = wr[k8];
        const float* hp = &hs[k8 * 8];
        a0 = fmaf(hp[0], bf2f((u16)wv[0]), a0);
        a1 = fmaf(hp[1], bf2f((u16)wv[1]), a1);
        a2 = fmaf(hp[2], bf2f((u16)wv[2]), a2);
        a3 = fmaf(hp[3], bf2f((u16)wv[3]), a3);
        a0 = fmaf(hp[4], bf2f((u16)wv[4]), a0);
        a1 = fmaf(hp[5], bf2f((u16)wv[5]), a1);
        a2 = fmaf(hp[6], bf2f((u16)wv[6]), a2);
        a3 = fmaf(hp[7], bf2f((u16)wv[7]), a3);
    }
    xbuf[row * 768 + col] += (a0 + a1) + (a2 + a3) + bo2[col];
}

// ---------------------------------------------------------------- layer-2 tiny FFN1 (relu -> bf16), 4 rows
__launch_bounds__(256)
__global__ void ffn1_tiny(const u16* __restrict__ h, const u16* __restrict__ W1T2,
                          const float* __restrict__ bf12, u16* __restrict__ big, int S)
{
    int b = blockIdx.y;
    int col = blockIdx.x * 256 + threadIdx.x;   // 0..3071
    long row = (long)b * SMAXT + (S - 1);
    __shared__ float hs[768];
    for (int i = threadIdx.x; i < 768; i += 256) hs[i] = bf2f(h[row * 768 + i]);
    __syncthreads();
    const short8* wr = (const short8*)(W1T2 + (long)col * 768);
    float a0 = 0.f, a1 = 0.f, a2 = 0.f, a3 = 0.f;
    #pragma unroll 4
    for (int k8 = 0; k8 < 96; ++k8) {
        short8 wv = wr[k8];
        const float* hp = &hs[k8 * 8];
        a0 = fmaf(hp[0], bf2f((u16)wv[0]), a0);
        a1 = fmaf(hp[1], bf2f((u16)wv[1]), a1);
        a2 = fmaf(hp[2], bf2f((u16)wv[2]), a2);
        a3 = fmaf(hp[3], bf2f((u16)wv[3]), a3);
        a0 = fmaf(hp[4], bf2f((u16)wv[4]), a0);
        a1 = fmaf(hp[5], bf2f((u16)wv[5]), a1);
        a2 = fmaf(hp[6], bf2f((u16)wv[6]), a2);
        a3 = fmaf(hp[7], bf2f((u16)wv[7]), a3);
    }
    float acc = (a0 + a1) + (a2 + a3) + bf12[col];
    big[row * 3072 + col] = f2bf(fmaxf(acc, 0.f));
}

// ---------------------------------------------------------------- layer-2 tiny FFN2 (+residual), 4 rows
__launch_bounds__(256)
__global__ void ffn2_tiny(const u16* __restrict__ big, const u16* __restrict__ W2T2,
                          const float* __restrict__ bf22, float* __restrict__ xbuf, int S)
{
    int b = blockIdx.y;
    int tid = threadIdx.x;
    int col = blockIdx.x * 64 + (tid & 63);
    int kg = tid >> 6;
    long row = (long)b * SMAXT + (S - 1);
    __shared__ float hs[3072];
    __shared__ float red[4][64];
    for (int i = tid; i < 3072; i += 256) hs[i] = bf2f(big[row * 3072 + i]);
    __syncthreads();
    const short8* wr = (const short8*)(W2T2 + (long)col * 3072 + kg * 768);
    const float* hp0 = &hs[kg * 768];
    float a0 = 0.f, a1 = 0.f, a2 = 0.f, a3 = 0.f;
    #pragma unroll 4
    for (int k8 = 0; k8 < 96; ++k8) {
        short8 wv = wr[k8];
        const float* hp = hp0 + k8 * 8;
        a0 = fmaf(hp[0], bf2f((u16)wv[0]), a0);
        a1 = fmaf(hp[1], bf2f((u16)wv[1]), a1);
        a2 = fmaf(hp[2], bf2f((u16)wv[2]), a2);
        a3 = fmaf(hp[3], bf2f((u16)wv[3]), a3);
        a0 = fmaf(hp[4], bf2f((u16)wv[4]), a0);
        a1 = fmaf(hp[5], bf2f((u16)wv[5]), a1);
        a2 = fmaf(hp[6], bf2f((u16)wv[6]), a2);
        a3 = fmaf(hp[7], bf2f((u16)wv[7]), a3);
    }
    red[kg][tid & 63] = (a0 + a1) + (a2 + a3);
    __syncthreads();
    if (kg == 0) {
        float acc = red[0][tid] + red[1][tid] + red[2][tid] + red[3][tid] + bf22[col];
        xbuf[row * 768 + col] += acc;
    }
}

// ---------------------------------------------------------------- decoder gelu GEMM (4x768 @ 768x768), fp32
__launch_bounds__(256)
__global__ void dec_gelu(const float* __restrict__ src, long srowstride,
                         const float* __restrict__ W, const float* __restrict__ bias,
                         float* __restrict__ dst)
{
    int b = blockIdx.y;
    int jb = blockIdx.x;
    __shared__ float s0buf[768];
    __shared__ float red[4][64];
    int tid = threadIdx.x;
    const float* sr = src + (long)b * srowstride;
    for (int i = tid; i < 768; i += 256) s0buf[i] = sr[i];
    __syncthreads();
    int jj = tid & 63, ig = tid >> 6;
    int jcol = jb * 64 + jj;
    float acc = 0.f;
    const float* wp = W + (long)(ig * 192) * 768 + jcol;
    #pragma unroll 4
    for (int i = 0; i < 192; ++i) acc += s0buf[ig * 192 + i] * wp[(long)i * 768];
    red[ig][jj] = acc;
    __syncthreads();
    if (ig == 0) {
        float a = red[0][jj] + red[1][jj] + red[2][jj] + red[3][jj] + bias[jcol];
        dst[(long)b * 768 + jcol] = gelu_f(a);
    }
}

// ---------------------------------------------------------------- decoder final (+ h0new = ln1(updated Xb row))
__launch_bounds__(256)
__global__ void dec_final(const float* __restrict__ d2, const float* __restrict__ Wd3,
                          const float* __restrict__ bd3, const float* __restrict__ Wpp,
                          const float* __restrict__ bpp, const float* __restrict__ gpp,
                          const float* __restrict__ bepp, float* __restrict__ out,
                          float* __restrict__ X, int t,
                          const float* __restrict__ g1l0, const float* __restrict__ be1l0,
                          u16* __restrict__ h0new)
{
    int b = blockIdx.x;
    int tid = threadIdx.x;
    __shared__ float red[2][4];
    __shared__ float pp[2];
    const float* dr = d2 + (long)b * 768;
    float a0 = 0.f, a1 = 0.f;
    for (int i = tid; i < 768; i += 256) {
        float v = dr[i];
        a0 += v * Wd3[2 * i]; a1 += v * Wd3[2 * i + 1];
    }
    for (int off = 32; off; off >>= 1) { a0 += __shfl_down(a0, off, 64); a1 += __shfl_down(a1, off, 64); }
    int wid = tid >> 6, lane = tid & 63;
    if (!lane) { red[0][wid] = a0; red[1][wid] = a1; }
    __syncthreads();
    if (!tid) {
        float p0 = red[0][0] + red[0][1] + red[0][2] + red[0][3] + bd3[0];
        float p1 = red[1][0] + red[1][1] + red[1][2] + red[1][3] + bd3[1];
        out[(long)(b * NFUT + t) * 2 + 0] = p0;
        out[(long)(b * NFUT + t) * 2 + 1] = p1;
        pp[0] = p0; pp[1] = p1;
    }
    __syncthreads();
    if (t == NFUT - 1) return;
    float p0 = pp[0], p1 = pp[1];
    float pv[3]; float s = 0.f;
    #pragma unroll
    for (int u = 0; u < 3; ++u) {
        int jcol = tid + 256 * u;
        pv[u] = p0 * Wpp[jcol] + p1 * Wpp[768 + jcol] + bpp[jcol];
        s += pv[u];
    }
    for (int off = 32; off; off >>= 1) s += __shfl_down(s, off, 64);
    __syncthreads();
    if (!lane) red[0][wid] = s;
    __syncthreads();
    float mean = (red[0][0] + red[0][1] + red[0][2] + red[0][3]) * (1.f / 768.f);
    float vs = 0.f;
    #pragma unroll
    for (int u = 0; u < 3; ++u) { float d = pv[u] - mean; vs += d * d; }
    for (int off = 32; off; off >>= 1) vs += __shfl_down(vs, off, 64);
    __syncthreads();
    if (!lane) red[1][wid] = vs;
    __syncthreads();
    float var = (red[1][0] + red[1][1] + red[1][2] + red[1][3]) * (1.f / 768.f);
    float inv = rsqrtf(var + 1e-5f);
    float* Xr = X + ((long)(b * SMAXT + CCTX + t + 1)) * 768;
    float xv[3];
    #pragma unroll
    for (int u = 0; u < 3; ++u) {
        int jcol = tid + 256 * u;
        float y = (pv[u] - mean) * inv * gpp[jcol] + bepp[jcol];
        float old = Xr[jcol];
        float nv = old + (y > 0.f ? y : 0.f);
        Xr[jcol] = nv;
        xv[u] = nv;
    }
    float xs = xv[0] + xv[1] + xv[2];
    for (int off = 32; off; off >>= 1) xs += __shfl_down(xs, off, 64);
    __syncthreads();
    if (!lane) red[0][wid] = xs;
    __syncthreads();
    float xmean = (red[0][0] + red[0][1] + red[0][2] + red[0][3]) * (1.f / 768.f);
    float xq = 0.f;
    #pragma unroll
    for (int u = 0; u < 3; ++u) { float d = xv[u] - xmean; xq += d * d; }
    for (int off = 32; off; off >>= 1) xq += __shfl_down(xq, off, 64);
    __syncthreads();
    if (!lane) red[1][wid] = xq;
    __syncthreads();
    float xvar = (red[1][0] + red[1][1] + red[1][2] + red[1][3]) * (1.f / 768.f);
    float xinv = rsqrtf(xvar + 1e-5f);
    #pragma unroll
    for (int u = 0; u < 3; ++u) {
        int jcol = tid + 256 * u;
        h0new[b * 768 + jcol] = f2bf((xv[u] - xmean) * xinv * g1l0[jcol] + be1l0[jcol]);
    }
}

// ---------------------------------------------------------------- launch
extern "C" void kernel_launch(void* const* d_in, const int* in_sizes, int n_in,
                              void* d_out, int out_size, void* d_ws, size_t ws_size,
                              hipStream_t stream)
{
    const float* img    = (const float*)d_in[0];
    const float* past   = (const float*)d_in[1];
    const int*   intent = (const int*)d_in[2];
    const float* pos    = (const float*)d_in[3];
    const float* futq   = (const float*)d_in[4];
    const float* iemb   = (const float*)d_in[5];
    const float* temb   = (const float*)d_in[6];
    const float* W_past = (const float*)d_in[7];
    const float* b_past = (const float*)d_in[8];
    const float* W_ppos = (const float*)d_in[9];
    const float* b_ppos = (const float*)d_in[10];
    const float* W_pp   = (const float*)d_in[11];
    const float* b_pp   = (const float*)d_in[12];
    const float* g_pp   = (const float*)d_in[13];
    const float* be_pp  = (const float*)d_in[14];
    const float* Wqkv   = (const float*)d_in[15];
    const float* bqkv   = (const float*)d_in[16];
    const float* Wo     = (const float*)d_in[17];
    const float* bo     = (const float*)d_in[18];
    const float* g1     = (const float*)d_in[19];
    const float* beta1  = (const float*)d_in[20];
    const float* g2     = (const float*)d_in[21];
    const float* beta2  = (const float*)d_in[22];
    const float* W1     = (const float*)d_in[23];
    const float* bf1    = (const float*)d_in[24];
    const float* W2     = (const float*)d_in[25];
    const float* bf2    = (const float*)d_in[26];
    const float* Wd1    = (const float*)d_in[27];
    const float* bd1    = (const float*)d_in[28];
    const float* Wd2    = (const float*)d_in[29];
    const float* bd2    = (const float*)d_in[30];
    const float* Wd3    = (const float*)d_in[31];
    const float* bd3    = (const float*)d_in[32];
    float* out = (float*)d_out;

    float* ws     = (float*)d_ws;
    float* Xb     = ws;                      // 900096 f
    float* xbuf   = ws + 900096;             // 900096 f
    float* qkvbuf = ws + 1800192;            // 2700288 f (layers 1-2, transient)
    u16*   hbuf   = (u16*)(ws + 4500480);    // 900096 bf16
    u16*   aobuf  = (u16*)(ws + 4950528);    // 900096 bf16 (layers 1-2)
    u16*   big    = (u16*)(ws + 5400576);    // 1172*3072 bf16
    float* d1ws   = ws + 7200768;            // 3072 f
    float* d2ws   = ws + 7203840;            // 3072 f
    u16*   WqkvT  = (u16*)(ws + 7206912);    // 3*2304*768 bf16
    u16*   WoT    = (u16*)(ws + 9861120);    // 3*768*768
    u16*   W1T    = (u16*)(ws + 10745856);   // 3*3072*768
    u16*   W2T    = (u16*)(ws + 14284800);   // 3*768*3072 (ends 17823744)
    float* qkv0   = ws + 17823744;           // 2700288 f (layer-0 persistent qkv)
    u16*   h0new  = (u16*)(ws + 20524032);   // 4*768 bf16 = 1536 f
    u16*   aobuf0 = (u16*)(ws + 20525568);   // 900096 bf16 = 450048 f (layer-0 persistent attn out)
    float* state  = ws + 20975616;           // 64*293*52 = 975104 f (layer-0 softmax state)

    // one-time per launch: weights -> bf16 [N,K]
    convert_transpose<<<dim3(2304/32, 768/32, 3), 256, 0, stream>>>(Wqkv, WqkvT, 768, 2304);
    convert_transpose<<<dim3(768/32, 768/32, 3), 256, 0, stream>>>(Wo, WoT, 768, 768);
    convert_transpose<<<dim3(3072/32, 768/32, 3), 256, 0, stream>>>(W1, W1T, 768, 3072);
    convert_transpose<<<dim3(768/32, 3072/32, 3), 256, 0, stream>>>(W2, W2T, 3072, 768);

    init_base<<<dim3(MROWS), dim3(256), 0, stream>>>(img, past, intent, pos, futq, iemb,
                                                     temb, W_past, b_past, W_ppos, b_ppos, Xb);

    for (int t = 0; t < NFUT; ++t) {
        int S = CCTX + t + 1;

        // ---------------- layer 0 (incremental QKV + incremental attention)
        if (t == 0) {
            ln_kernel<<<dim3(293), dim3(256), 0, stream>>>(Xb, g1, beta1, hbuf);
            gemm_mfma<64, 64, 2, 1><<<dim3(36, 19), dim3(256), 0, stream>>>(
                hbuf, WqkvT, bqkv, nullptr, qkv0, MROWS, 2304, 768, 0);
            attn_kernel<<<dim3((S + 15) / 16, 64), dim3(256), 0, stream>>>(qkv0, aobuf0, S, state, 0);
        } else {
            qkv_update<<<dim3(9, 4), dim3(256), 0, stream>>>(h0new, 768L, WqkvT, bqkv, qkv0, CCTX + t);
            attn0_inc<<<dim3(128), dim3(256), 0, stream>>>(qkv0, state, aobuf0, S);
        }
        gemm_mfma<64, 32, 0, 1><<<dim3(24, 19), dim3(256), 0, stream>>>(
            aobuf0, WoT, bo, Xb, xbuf, MROWS, 768, 768, 0);
        ln_kernel<<<dim3(293), dim3(256), 0, stream>>>(xbuf, g2, beta2, hbuf);
        gemm_mfma<64, 64, 1, 1><<<dim3(48, 19), dim3(256), 0, stream>>>(
            hbuf, W1T, bf1, nullptr, big, MROWS, 3072, 768, 0);
        gemm_mfma<64, 32, 3, 4><<<dim3(24, 19, 4), dim3(256), 0, stream>>>(   // split-K atomic FFN2
            big, W2T, bf2, nullptr, xbuf, MROWS, 768, 3072, 0);

        // ---------------- layer 1 (full)
        ln_kernel<<<dim3(293), dim3(256), 0, stream>>>(xbuf, g1 + 768, beta1 + 768, hbuf);
        gemm_mfma<64, 64, 2, 1><<<dim3(36, 19), dim3(256), 0, stream>>>(
            hbuf, WqkvT + 1L * 768 * 2304, bqkv + 2304, nullptr, qkvbuf, MROWS, 2304, 768, 0);
        attn_kernel<<<dim3((S + 15) / 16, 64), dim3(256), 0, stream>>>(qkvbuf, aobuf, S, nullptr, 0);
        gemm_mfma<64, 32, 0, 1><<<dim3(24, 19), dim3(256), 0, stream>>>(
            aobuf, WoT + 1L * 768 * 768, bo + 768, xbuf, xbuf, MROWS, 768, 768, 0);
        ln_kernel<<<dim3(293), dim3(256), 0, stream>>>(xbuf, g2 + 768, beta2 + 768, hbuf);
        gemm_mfma<64, 64, 1, 1><<<dim3(48, 19), dim3(256), 0, stream>>>(
            hbuf, W1T + 1L * 768 * 3072, bf1 + 3072, nullptr, big, MROWS, 3072, 768, 0);
        gemm_mfma<64, 32, 3, 4><<<dim3(24, 19, 4), dim3(256), 0, stream>>>(   // split-K atomic FFN2
            big, W2T + 1L * 3072 * 768, bf2 + 768, nullptr, xbuf, MROWS, 768, 3072, 0);

        // ---------------- layer 2 (K/V full, everything else only row S-1)
        ln_kernel<<<dim3(293), dim3(256), 0, stream>>>(xbuf, g1 + 2 * 768, beta1 + 2 * 768, hbuf);
        gemm_mfma<64, 32, 2, 1><<<dim3(48, 19), dim3(256), 0, stream>>>(     // K,V planes, cols 768..2303
            hbuf, WqkvT + 2L * 768 * 2304, bqkv + 2 * 2304, nullptr, qkvbuf, MROWS, 2304, 768, 768);
        qkv_update<<<dim3(3, 4), dim3(256), 0, stream>>>(                     // Q row S-1 (cols 0..767)
            hbuf + (long)(S - 1) * 768, (long)SMAXT * 768,
            WqkvT + 2L * 768 * 2304, bqkv + 2 * 2304, qkvbuf, S - 1);
        attn_kernel<<<dim3(1, 64), dim3(256), 0, stream>>>(qkvbuf, aobuf, S, nullptr, S - 16);
        otiny_kernel<<<dim3(3, 4), dim3(256), 0, stream>>>(aobuf, WoT + 2L * 768 * 768, bo + 2 * 768, xbuf, S);
        ln4_kernel<<<dim3(1), dim3(256), 0, stream>>>(xbuf, g2 + 2 * 768, beta2 + 2 * 768, hbuf, S);
        ffn1_tiny<<<dim3(12, 4), dim3(256), 0, stream>>>(hbuf, W1T + 2L * 768 * 3072, bf1 + 2 * 3072, big, S);
        ffn2_tiny<<<dim3(12, 4), dim3(256), 0, stream>>>(big, W2T + 2L * 3072 * 768, bf2 + 2 * 768, xbuf, S);

        // ---------------- decoder
        dec_gelu<<<dim3(12, 4), dim3(256), 0, stream>>>(xbuf + (long)(S - 1) * 768, (long)SMAXT * 768, Wd1, bd1, d1ws);
        dec_gelu<<<dim3(12, 4), dim3(256), 0, stream>>>(d1ws, 768L, Wd2, bd2, d2ws);
        dec_final<<<dim3(4), dim3(256), 0, stream>>>(d2ws, Wd3, bd3, W_pp, b_pp, g_pp, be_pp, out, Xb, t,
                                                     g1, beta1, h0new);
    }
}